// Round 3
// baseline (384.919 us; speedup 1.0000x reference)
//
#include <hip/hip_runtime.h>
#include <hip/hip_bf16.h>
#include <type_traits>

#define D_MODEL 1024
#define NH 16
#define DKH 64
#define BB 2
#define SS 2048

typedef __hip_bfloat16 bf16;
typedef __attribute__((ext_vector_type(8))) short short8;
typedef __attribute__((ext_vector_type(4))) short short4v;
typedef __attribute__((ext_vector_type(4))) float floatx4;

__device__ __forceinline__ float bf2f(bf16 x) { return __bfloat162float(x); }
__device__ __forceinline__ bf16 f2bf(float x) { return __float2bfloat16(x); }

// ---------------------------------------------------------------------------
// GEMM: C[m][n] = sum_k A[m][k] * W[n][k] + bias[n]
// M=4096, N=1024, K=1024. 128x128 tile, BK=32, 256 threads (4 waves),
// each wave computes 64x64 via 4x4 MFMA 16x16x32 bf16 tiles.
// Inputs/weights are FP32 storage (bf16-rounded values); converted to bf16
// while staging into LDS. TIN selects the A-matrix storage dtype; TOUT the
// C storage dtype.
// ---------------------------------------------------------------------------
template <typename TIN, typename TOUT>
__device__ __forceinline__ void gemm_body(const TIN* __restrict__ A,
                                          const float* __restrict__ W,
                                          const float* __restrict__ Bi,
                                          TOUT* __restrict__ C) {
  constexpr int N = 1024, K = 1024;
  constexpr int LDR = 32;
  __shared__ bf16 As[128 * LDR];
  __shared__ bf16 Bs[128 * LDR];

  const int tid = threadIdx.x;
  const int w = tid >> 6, lane = tid & 63, quad = lane >> 4, n16 = lane & 15;
  const int bm = blockIdx.y, bn = blockIdx.x;
  const int wm = (w & 1) * 64, wn = (w >> 1) * 64;

  floatx4 acc[4][4] = {};

  const float* Wf = W + (size_t)(bn * 128) * K;

  for (int k0 = 0; k0 < K; k0 += 32) {
    // ---- stage A ----
    if constexpr (std::is_same<TIN, float>::value) {
      const float* Af = A + (size_t)(bm * 128) * K;
#pragma unroll
      for (int ii = 0; ii < 4; ii++) {
        const int id = ii * 256 + tid;       // 0..1023
        const int row = id >> 3, c = id & 7; // 128 rows x 8 float4-chunks
        const float4 va = *(const float4*)(Af + (size_t)row * K + k0 + c * 4);
        short4v sa;
        bf16* pb = (bf16*)&sa;
        pb[0] = f2bf(va.x); pb[1] = f2bf(va.y);
        pb[2] = f2bf(va.z); pb[3] = f2bf(va.w);
        *(short4v*)(&As[row * LDR + c * 4]) = sa;
      }
    } else {
      const int r0 = tid >> 2;  // 0..63 (and +64)
      const int c0 = tid & 3;   // 16B chunk of 8 bf16
      const bf16* Ag = A + (size_t)(bm * 128 + r0) * K + c0 * 8 + k0;
      short8 a0 = *(const short8*)(Ag);
      short8 a1 = *(const short8*)(Ag + (size_t)64 * K);
      *(short8*)(&As[r0 * LDR + c0 * 8]) = a0;
      *(short8*)(&As[(r0 + 64) * LDR + c0 * 8]) = a1;
    }
    // ---- stage W (always fp32) ----
#pragma unroll
    for (int ii = 0; ii < 4; ii++) {
      const int id = ii * 256 + tid;
      const int row = id >> 3, c = id & 7;
      const float4 vw = *(const float4*)(Wf + (size_t)row * K + k0 + c * 4);
      short4v sw;
      bf16* pb = (bf16*)&sw;
      pb[0] = f2bf(vw.x); pb[1] = f2bf(vw.y);
      pb[2] = f2bf(vw.z); pb[3] = f2bf(vw.w);
      *(short4v*)(&Bs[row * LDR + c * 4]) = sw;
    }
    __syncthreads();

    short8 af[4], bfr[4];
#pragma unroll
    for (int i = 0; i < 4; i++)
      af[i] = *(const short8*)(&As[(wm + i * 16 + n16) * LDR + quad * 8]);
#pragma unroll
    for (int j = 0; j < 4; j++)
      bfr[j] = *(const short8*)(&Bs[(wn + j * 16 + n16) * LDR + quad * 8]);
#pragma unroll
    for (int i = 0; i < 4; i++)
#pragma unroll
      for (int j = 0; j < 4; j++)
        acc[i][j] = __builtin_amdgcn_mfma_f32_16x16x32_bf16(af[i], bfr[j], acc[i][j], 0, 0, 0);
    __syncthreads();
  }

  float bv[4];
#pragma unroll
  for (int j = 0; j < 4; j++) bv[j] = Bi[bn * 128 + wn + j * 16 + n16];

#pragma unroll
  for (int i = 0; i < 4; i++) {
    const int rowb = bm * 128 + wm + i * 16 + quad * 4;
#pragma unroll
    for (int j = 0; j < 4; j++) {
      const int col = bn * 128 + wn + j * 16 + n16;
#pragma unroll
      for (int r = 0; r < 4; r++) {
        const float v = acc[i][j][r] + bv[j];
        if constexpr (std::is_same<TOUT, float>::value)
          C[(size_t)(rowb + r) * N + col] = v;
        else
          C[(size_t)(rowb + r) * N + col] = f2bf(v);
      }
    }
  }
}

__global__ __launch_bounds__(256) void gemm_qkv_kernel(
    const float* __restrict__ q_in, const float* __restrict__ k_in,
    const float* __restrict__ v_in, const float* __restrict__ wq,
    const float* __restrict__ bq, const float* __restrict__ wk,
    const float* __restrict__ bk, const float* __restrict__ wv,
    const float* __restrict__ bv, bf16* __restrict__ out_base) {
  const int z = blockIdx.z;
  const float* A = (z == 0) ? q_in : (z == 1) ? k_in : v_in;
  const float* W = (z == 0) ? wq : (z == 1) ? wk : wv;
  const float* Bi = (z == 0) ? bq : (z == 1) ? bk : bv;
  bf16* C = out_base + (size_t)z * (size_t)(BB * SS) * D_MODEL;
  gemm_body<float, bf16>(A, W, Bi, C);
}

__global__ __launch_bounds__(256) void gemm_out_kernel(
    const bf16* __restrict__ A, const float* __restrict__ W,
    const float* __restrict__ Bi, float* __restrict__ C) {
  gemm_body<bf16, float>(A, W, Bi, C);
}

// ---------------------------------------------------------------------------
// Flash attention: one block per (b, h, 64-row q tile). 4 waves x 16 q-rows.
// K/V tiles of 64 rows staged in LDS (V transposed). Online softmax.
// Causal mask applied analytically (mask input ignored).
// O may alias Q: each block reads only its own Q rows (into registers, at
// kernel start) and writes exactly that region at the end.
// ---------------------------------------------------------------------------
__global__ __launch_bounds__(256) void attn_kernel(const bf16* __restrict__ Q,
                                                   const bf16* __restrict__ Kb,
                                                   const bf16* __restrict__ Vb,
                                                   bf16* __restrict__ O) {
  constexpr int LDR = 72;  // 144B row stride (multiple of 16B)
  __shared__ bf16 Ks[64 * LDR];      // [kv][d]
  __shared__ bf16 Vt[64 * LDR];      // [d][kv]  (transposed)
  __shared__ bf16 Pw[4 * 16 * LDR];  // per-wave P tile [16][64]

  const int tid = threadIdx.x;
  const int w = tid >> 6, lane = tid & 63, quad = lane >> 4, n16 = lane & 15;
  const int qb = blockIdx.x, h = blockIdx.y, b = blockIdx.z;
  const int q0 = qb * 64;
  const int q0w = q0 + w * 16;
  const size_t headoff = ((size_t)b * SS) * D_MODEL + h * DKH;

  // Q fragments (A-operand layout: m = n16, k = step*32 + quad*8 + j)
  short8 aQ[2];
  {
    const bf16* qp = Q + headoff + (size_t)(q0w + n16) * D_MODEL + quad * 8;
    aQ[0] = *(const short8*)(qp);
    aQ[1] = *(const short8*)(qp + 32);
  }

  floatx4 facc[4] = {};
  float m_i[4], l_i[4];
#pragma unroll
  for (int r = 0; r < 4; r++) { m_i[r] = -1e30f; l_i[r] = 0.f; }

  const int kvr0 = tid >> 3;  // 0..31 (and +32)
  const int ch = tid & 7;     // 8-elem chunk along d

  for (int t = 0; t <= qb; ++t) {
    const int kv0 = t * 64;
#pragma unroll
    for (int i = 0; i < 2; i++) {
      const int kvr = kvr0 + i * 32;
      short8 k8 = *(const short8*)(Kb + headoff + (size_t)(kv0 + kvr) * D_MODEL + ch * 8);
      *(short8*)(&Ks[kvr * LDR + ch * 8]) = k8;
      short8 v8 = *(const short8*)(Vb + headoff + (size_t)(kv0 + kvr) * D_MODEL + ch * 8);
      const bf16* vb8 = (const bf16*)&v8;
#pragma unroll
      for (int s2 = 0; s2 < 8; s2++) {
        const int jj = (s2 + ch) & 7;
        Vt[(ch * 8 + jj) * LDR + kvr] = vb8[jj];
      }
    }
    __syncthreads();

    // ---- S = Q K^T ----
    floatx4 sacc[4];
#pragma unroll
    for (int blk = 0; blk < 4; blk++) {
      floatx4 z = {};
      short8 bk0 = *(const short8*)(&Ks[(blk * 16 + n16) * LDR + quad * 8]);
      short8 bk1 = *(const short8*)(&Ks[(blk * 16 + n16) * LDR + 32 + quad * 8]);
      z = __builtin_amdgcn_mfma_f32_16x16x32_bf16(aQ[0], bk0, z, 0, 0, 0);
      z = __builtin_amdgcn_mfma_f32_16x16x32_bf16(aQ[1], bk1, z, 0, 0, 0);
      sacc[blk] = z;
    }

    // ---- mask + online softmax (rows = quad*4+r, cols = blk*16+n16) ----
    float pv[4][4], mt[4];
#pragma unroll
    for (int r = 0; r < 4; r++) mt[r] = -1e30f;
    const int qrow_base = q0w + quad * 4;
#pragma unroll
    for (int blk = 0; blk < 4; blk++) {
      const int kvg = kv0 + blk * 16 + n16;
#pragma unroll
      for (int r = 0; r < 4; r++) {
        float s = sacc[blk][r] * 0.125f;
        if (kvg > qrow_base + r) s = -1e30f;
        pv[blk][r] = s;
        mt[r] = fmaxf(mt[r], s);
      }
    }
#pragma unroll
    for (int off = 1; off < 16; off <<= 1)
#pragma unroll
      for (int r = 0; r < 4; r++) mt[r] = fmaxf(mt[r], __shfl_xor(mt[r], off, 64));

    float alpha[4], rs[4];
#pragma unroll
    for (int r = 0; r < 4; r++) {
      const float mn = fmaxf(m_i[r], mt[r]);
      alpha[r] = __expf(m_i[r] - mn);
      m_i[r] = mn;
      float loc = 0.f;
#pragma unroll
      for (int blk = 0; blk < 4; blk++) {
        const float p = __expf(pv[blk][r] - mn);
        pv[blk][r] = p;
        loc += p;
      }
      rs[r] = loc;
    }
#pragma unroll
    for (int off = 1; off < 16; off <<= 1)
#pragma unroll
      for (int r = 0; r < 4; r++) rs[r] += __shfl_xor(rs[r], off, 64);
#pragma unroll
    for (int r = 0; r < 4; r++) l_i[r] = l_i[r] * alpha[r] + rs[r];
#pragma unroll
    for (int d = 0; d < 4; d++)
#pragma unroll
      for (int r = 0; r < 4; r++) facc[d][r] *= alpha[r];

    // ---- P: C-layout -> LDS -> A-operand layout ----
    bf16* pw = &Pw[w * 16 * LDR];
#pragma unroll
    for (int blk = 0; blk < 4; blk++)
#pragma unroll
      for (int r = 0; r < 4; r++)
        pw[(quad * 4 + r) * LDR + blk * 16 + n16] = f2bf(pv[blk][r]);

    short8 aP0 = *(const short8*)(&pw[n16 * LDR + quad * 8]);
    short8 aP1 = *(const short8*)(&pw[n16 * LDR + 32 + quad * 8]);

    // ---- O += P V ----
#pragma unroll
    for (int d = 0; d < 4; d++) {
      short8 bv0 = *(const short8*)(&Vt[(d * 16 + n16) * LDR + quad * 8]);
      short8 bv1 = *(const short8*)(&Vt[(d * 16 + n16) * LDR + 32 + quad * 8]);
      facc[d] = __builtin_amdgcn_mfma_f32_16x16x32_bf16(aP0, bv0, facc[d], 0, 0, 0);
      facc[d] = __builtin_amdgcn_mfma_f32_16x16x32_bf16(aP1, bv1, facc[d], 0, 0, 0);
    }
    __syncthreads();
  }

  // ---- epilogue: O /= l, store (aliases Q region of this block only) ----
#pragma unroll
  for (int r = 0; r < 4; r++) {
    const float inv = 1.f / l_i[r];
    const int qrow = q0w + quad * 4 + r;
    bf16* op = O + headoff + (size_t)qrow * D_MODEL;
#pragma unroll
    for (int d = 0; d < 4; d++) op[d * 16 + n16] = f2bf(facc[d][r] * inv);
  }
}

// ---------------------------------------------------------------------------
extern "C" void kernel_launch(void* const* d_in, const int* in_sizes, int n_in,
                              void* d_out, int out_size, void* d_ws, size_t ws_size,
                              hipStream_t stream) {
  (void)in_sizes; (void)n_in; (void)out_size; (void)ws_size;
  const float* query  = (const float*)d_in[0];
  const float* key_in = (const float*)d_in[1];
  const float* value  = (const float*)d_in[2];
  // d_in[3] = mask (int32) — causal, applied analytically
  const float* w_q = (const float*)d_in[4];
  const float* b_q = (const float*)d_in[5];
  const float* w_k = (const float*)d_in[6];
  const float* b_k = (const float*)d_in[7];
  const float* w_v = (const float*)d_in[8];
  const float* b_v = (const float*)d_in[9];
  const float* w_o = (const float*)d_in[10];
  const float* b_o = (const float*)d_in[11];
  float* outp = (float*)d_out;

  const size_t mat = (size_t)(BB * SS) * D_MODEL;  // 4096*1024
  bf16* Qws = (bf16*)d_ws;
  bf16* Kws = Qws + mat;
  bf16* Vws = Kws + mat;
  bf16* Ows = Qws;  // O aliases Q (block-exclusive regions; Q read first)

  // QKV projections (fused into one launch via blockIdx.z)
  dim3 gq(D_MODEL / 128, (BB * SS) / 128, 3);
  gemm_qkv_kernel<<<gq, 256, 0, stream>>>(query, key_in, value, w_q, b_q, w_k,
                                          b_k, w_v, b_v, Qws);
  // attention
  dim3 ga(SS / 64, NH, BB);
  attn_kernel<<<ga, 256, 0, stream>>>(Qws, Kws, Vws, Ows);
  // output projection
  dim3 go(D_MODEL / 128, (BB * SS) / 128, 1);
  gemm_out_kernel<<<go, 256, 0, stream>>>(Ows, w_o, b_o, outp);
}

// Round 4
// 341.435 us; speedup vs baseline: 1.1274x; 1.1274x over previous
//
#include <hip/hip_runtime.h>
#include <hip/hip_bf16.h>
#include <type_traits>

#define D_MODEL 1024
#define NH 16
#define DKH 64
#define BB 2
#define SS 2048
#define MTOT (BB * SS)  // 4096

typedef __hip_bfloat16 bf16;
typedef __attribute__((ext_vector_type(8))) short short8;
typedef __attribute__((ext_vector_type(4))) short short4v;
typedef __attribute__((ext_vector_type(4))) float floatx4;

__device__ __forceinline__ bf16 f2bf(float x) { return __float2bfloat16(x); }

// ---------------------------------------------------------------------------
// GEMM: C[m][n] = sum_k A[m][k] * W[n][k] + bias[n],  M=4096, N=K=1024.
// 128x128 tile, BK=32, 4 waves, 4x4 MFMA 16x16x32 bf16 per wave.
// Register-prefetch software pipeline: tile k+1 loaded into VGPRs while tile k
// computes (hides fp32 global latency that made round-2 GEMM 4000 cyc/iter).
// mode: 0 = bf16 row-major C; 1 = bf16 V^T layout [n][m] (m-contiguous);
//       2 = fp32 row-major C.
// ---------------------------------------------------------------------------
template <typename TIN>
__device__ __forceinline__ void gemm_body(const TIN* __restrict__ A,
                                          const float* __restrict__ W,
                                          const float* __restrict__ Bi,
                                          void* __restrict__ Cv, int mode) {
  constexpr int N = 1024, K = 1024, LDR = 32;
  __shared__ bf16 As[128 * LDR];
  __shared__ bf16 Bs[128 * LDR];
  const int tid = threadIdx.x;
  const int w = tid >> 6, lane = tid & 63, quad = lane >> 4, n16 = lane & 15;
  const int bm = blockIdx.y, bn = blockIdx.x;
  const int wm = (w & 1) * 64, wn = (w >> 1) * 64;
  const int row8 = tid >> 3, c8 = tid & 7;  // fp32 staging map (+32 rows per ii)
  const int r0 = tid >> 2, c0 = tid & 3;    // bf16 staging map

  const float* Wf = W + (size_t)(bn * 128) * K;

  float4 pw4[4];
  float4 pa4[4];
  short8 pa8[2];

  auto loadW = [&](int kk) {
#pragma unroll
    for (int ii = 0; ii < 4; ii++)
      pw4[ii] = *(const float4*)(Wf + (size_t)(ii * 32 + row8) * K + kk + c8 * 4);
  };
  auto loadA = [&](int kk) {
    if constexpr (std::is_same<TIN, float>::value) {
      const float* Af = A + (size_t)(bm * 128) * K;
#pragma unroll
      for (int ii = 0; ii < 4; ii++)
        pa4[ii] = *(const float4*)(Af + (size_t)(ii * 32 + row8) * K + kk + c8 * 4);
    } else {
      const bf16* Ab = A + (size_t)(bm * 128 + r0) * K + c0 * 8 + kk;
      pa8[0] = *(const short8*)(Ab);
      pa8[1] = *(const short8*)(Ab + (size_t)64 * K);
    }
  };
  auto stage = [&]() {
#pragma unroll
    for (int ii = 0; ii < 4; ii++) {
      short4v s;
      bf16* pb = (bf16*)&s;
      pb[0] = f2bf(pw4[ii].x); pb[1] = f2bf(pw4[ii].y);
      pb[2] = f2bf(pw4[ii].z); pb[3] = f2bf(pw4[ii].w);
      *(short4v*)(&Bs[(ii * 32 + row8) * LDR + c8 * 4]) = s;
    }
    if constexpr (std::is_same<TIN, float>::value) {
#pragma unroll
      for (int ii = 0; ii < 4; ii++) {
        short4v s;
        bf16* pb = (bf16*)&s;
        pb[0] = f2bf(pa4[ii].x); pb[1] = f2bf(pa4[ii].y);
        pb[2] = f2bf(pa4[ii].z); pb[3] = f2bf(pa4[ii].w);
        *(short4v*)(&As[(ii * 32 + row8) * LDR + c8 * 4]) = s;
      }
    } else {
      *(short8*)(&As[r0 * LDR + c0 * 8]) = pa8[0];
      *(short8*)(&As[(r0 + 64) * LDR + c0 * 8]) = pa8[1];
    }
  };

  floatx4 acc[4][4] = {};
  loadA(0);
  loadW(0);
  for (int k0 = 0; k0 < K; k0 += 32) {
    stage();
    __syncthreads();
    if (k0 + 32 < K) { loadA(k0 + 32); loadW(k0 + 32); }  // prefetch next tile
    short8 af[4], bfr[4];
#pragma unroll
    for (int i = 0; i < 4; i++)
      af[i] = *(const short8*)(&As[(wm + i * 16 + n16) * LDR + quad * 8]);
#pragma unroll
    for (int j = 0; j < 4; j++)
      bfr[j] = *(const short8*)(&Bs[(wn + j * 16 + n16) * LDR + quad * 8]);
#pragma unroll
    for (int i = 0; i < 4; i++)
#pragma unroll
      for (int j = 0; j < 4; j++)
        acc[i][j] = __builtin_amdgcn_mfma_f32_16x16x32_bf16(af[i], bfr[j], acc[i][j], 0, 0, 0);
    __syncthreads();
  }

  float bv[4];
#pragma unroll
  for (int j = 0; j < 4; j++) bv[j] = Bi[bn * 128 + wn + j * 16 + n16];

#pragma unroll
  for (int i = 0; i < 4; i++) {
    const int rowb = bm * 128 + wm + i * 16 + quad * 4;
#pragma unroll
    for (int j = 0; j < 4; j++) {
      const int col = bn * 128 + wn + j * 16 + n16;
      if (mode == 1) {
        short4v s;
        bf16* pb = (bf16*)&s;
#pragma unroll
        for (int r = 0; r < 4; r++) pb[r] = f2bf(acc[i][j][r] + bv[j]);
        *(short4v*)((bf16*)Cv + (size_t)col * MTOT + rowb) = s;
      } else if (mode == 0) {
        bf16* C = (bf16*)Cv;
#pragma unroll
        for (int r = 0; r < 4; r++)
          C[(size_t)(rowb + r) * N + col] = f2bf(acc[i][j][r] + bv[j]);
      } else {
        float* C = (float*)Cv;
#pragma unroll
        for (int r = 0; r < 4; r++)
          C[(size_t)(rowb + r) * N + col] = acc[i][j][r] + bv[j];
      }
    }
  }
}

__global__ __launch_bounds__(256) void gemm_qkv_kernel(
    const float* __restrict__ q_in, const float* __restrict__ k_in,
    const float* __restrict__ v_in, const float* __restrict__ wq,
    const float* __restrict__ bq, const float* __restrict__ wk,
    const float* __restrict__ bk, const float* __restrict__ wv,
    const float* __restrict__ bv, bf16* __restrict__ Qw,
    bf16* __restrict__ Kw, bf16* __restrict__ VTw) {
  const int z = blockIdx.z;
  const float* A = (z == 0) ? q_in : (z == 1) ? k_in : v_in;
  const float* W = (z == 0) ? wq : (z == 1) ? wk : wv;
  const float* Bi = (z == 0) ? bq : (z == 1) ? bk : bv;
  void* C = (z == 0) ? (void*)Qw : (z == 1) ? (void*)Kw : (void*)VTw;
  gemm_body<float>(A, W, Bi, C, (z == 2) ? 1 : 0);
}

__global__ __launch_bounds__(256) void gemm_out_kernel(
    const bf16* __restrict__ A, const float* __restrict__ W,
    const float* __restrict__ Bi, float* __restrict__ C) {
  gemm_body<bf16>(A, W, Bi, (void*)C, 2);
}

// ---------------------------------------------------------------------------
// Flash attention. Grid (16, NH, BB): block p handles q-tiles p and 31-p
// (uniform 17 KV-iterations per block -> no triangular tail). 4 waves x 16
// q-rows. KV tile BN=128 staged via reg-prefetch; V arrives pre-transposed
// [d][s] from the V-projection GEMM (no in-kernel transpose). O aliases Q:
// each (rows,cols) region is touched only by its own block, Q read first.
// ---------------------------------------------------------------------------
__global__ __launch_bounds__(256) void attn_kernel(const bf16* __restrict__ Q,
                                                   const bf16* __restrict__ Kg,
                                                   const bf16* __restrict__ VT,
                                                   bf16* __restrict__ O) {
  constexpr int BN = 128, LDK = 72, LDV = 136, LDP = 136;
  __shared__ bf16 Ks[128 * LDK];      // [kv][d]
  __shared__ bf16 Vs[64 * LDV];       // [d][kv]
  __shared__ bf16 Pw[4 * 16 * LDP];   // per-wave P [16][128]

  const int tid = threadIdx.x;
  const int w = tid >> 6, lane = tid & 63, quad = lane >> 4, n16 = lane & 15;
  const int p = blockIdx.x, h = blockIdx.y, b = blockIdx.z;
  const size_t qoff = (size_t)b * SS * D_MODEL + h * DKH;
  const bf16* VTh = VT + (size_t)(h * DKH) * MTOT + (size_t)b * SS;

  const int kvr = tid >> 3, ck = tid & 7;  // K staging (+32 rows per ii)
  const int dd = tid >> 4, cv = tid & 15;  // V staging (+16 rows per ii)

  short8 kreg[4], vreg[4];
  auto loadKV = [&](int kv0) {
#pragma unroll
    for (int ii = 0; ii < 4; ii++) {
      kreg[ii] = *(const short8*)(Kg + qoff + (size_t)(kv0 + ii * 32 + kvr) * D_MODEL + ck * 8);
      vreg[ii] = *(const short8*)(VTh + (size_t)(ii * 16 + dd) * MTOT + kv0 + cv * 8);
    }
  };

  for (int hf = 0; hf < 2; hf++) {
    const int q0 = (hf == 0) ? p * 64 : (31 - p) * 64;
    const int q0w = q0 + w * 16;
    const int nt = (q0 + 191) >> 7;

    short8 aQ0, aQ1;
    {
      const bf16* qp = Q + qoff + (size_t)(q0w + n16) * D_MODEL + quad * 8;
      aQ0 = *(const short8*)(qp);
      aQ1 = *(const short8*)(qp + 32);
    }

    floatx4 facc[4] = {};
    float m_i[4], l_i[4];
#pragma unroll
    for (int r = 0; r < 4; r++) { m_i[r] = -1e30f; l_i[r] = 0.f; }

    loadKV(0);
    for (int t = 0; t < nt; t++) {
      // ---- stage current tile from prefetch regs ----
#pragma unroll
      for (int ii = 0; ii < 4; ii++) {
        *(short8*)(&Ks[(ii * 32 + kvr) * LDK + ck * 8]) = kreg[ii];
        *(short8*)(&Vs[(ii * 16 + dd) * LDV + cv * 8]) = vreg[ii];
      }
      __syncthreads();
      if (t + 1 < nt) loadKV((t + 1) * BN);  // prefetch next tile

      const int kv0 = t * BN;
      // ---- S = Q K^T (+ mask + running row max) ----
      float pv[8][4];
      float mt[4] = {-1e30f, -1e30f, -1e30f, -1e30f};
      const int qrow_base = q0w + quad * 4;
#pragma unroll
      for (int blk = 0; blk < 8; blk++) {
        floatx4 z = {};
        short8 bk0 = *(const short8*)(&Ks[(blk * 16 + n16) * LDK + quad * 8]);
        short8 bk1 = *(const short8*)(&Ks[(blk * 16 + n16) * LDK + 32 + quad * 8]);
        z = __builtin_amdgcn_mfma_f32_16x16x32_bf16(aQ0, bk0, z, 0, 0, 0);
        z = __builtin_amdgcn_mfma_f32_16x16x32_bf16(aQ1, bk1, z, 0, 0, 0);
        const int kvg = kv0 + blk * 16 + n16;
#pragma unroll
        for (int r = 0; r < 4; r++) {
          float s = z[r] * 0.125f;
          if (kvg > qrow_base + r) s = -1e30f;
          pv[blk][r] = s;
          mt[r] = fmaxf(mt[r], s);
        }
      }
#pragma unroll
      for (int off = 1; off < 16; off <<= 1)
#pragma unroll
        for (int r = 0; r < 4; r++) mt[r] = fmaxf(mt[r], __shfl_xor(mt[r], off, 64));

      float alpha[4];
#pragma unroll
      for (int r = 0; r < 4; r++) {
        const float mn = fmaxf(m_i[r], mt[r]);
        alpha[r] = __expf(m_i[r] - mn);
        m_i[r] = mn;
      }
      float rs[4] = {0.f, 0.f, 0.f, 0.f};
#pragma unroll
      for (int blk = 0; blk < 8; blk++)
#pragma unroll
        for (int r = 0; r < 4; r++) {
          const float pe = __expf(pv[blk][r] - m_i[r]);
          pv[blk][r] = pe;
          rs[r] += pe;
        }
#pragma unroll
      for (int off = 1; off < 16; off <<= 1)
#pragma unroll
        for (int r = 0; r < 4; r++) rs[r] += __shfl_xor(rs[r], off, 64);
#pragma unroll
      for (int r = 0; r < 4; r++) l_i[r] = l_i[r] * alpha[r] + rs[r];
#pragma unroll
      for (int d = 0; d < 4; d++)
#pragma unroll
        for (int r = 0; r < 4; r++) facc[d][r] *= alpha[r];

      // ---- P: C-layout -> LDS -> A-operand layout (wave-private) ----
      bf16* pw = &Pw[w * 16 * LDP];
#pragma unroll
      for (int blk = 0; blk < 8; blk++)
#pragma unroll
        for (int r = 0; r < 4; r++)
          pw[(quad * 4 + r) * LDP + blk * 16 + n16] = f2bf(pv[blk][r]);

      short8 aP[4];
#pragma unroll
      for (int c = 0; c < 4; c++)
        aP[c] = *(const short8*)(&pw[n16 * LDP + c * 32 + quad * 8]);

      // ---- O += P V ----
#pragma unroll
      for (int d = 0; d < 4; d++)
#pragma unroll
        for (int c = 0; c < 4; c++) {
          short8 bvf = *(const short8*)(&Vs[(d * 16 + n16) * LDV + c * 32 + quad * 8]);
          facc[d] = __builtin_amdgcn_mfma_f32_16x16x32_bf16(aP[c], bvf, facc[d], 0, 0, 0);
        }
      __syncthreads();
    }

    // ---- epilogue: O /= l ----
#pragma unroll
    for (int r = 0; r < 4; r++) {
      const float inv = 1.f / l_i[r];
      const int qrow = q0w + quad * 4 + r;
      bf16* op = O + qoff + (size_t)qrow * D_MODEL;
#pragma unroll
      for (int d = 0; d < 4; d++) op[d * 16 + n16] = f2bf(facc[d][r] * inv);
    }
  }
}

// ---------------------------------------------------------------------------
extern "C" void kernel_launch(void* const* d_in, const int* in_sizes, int n_in,
                              void* d_out, int out_size, void* d_ws, size_t ws_size,
                              hipStream_t stream) {
  (void)in_sizes; (void)n_in; (void)out_size; (void)ws_size;
  const float* query  = (const float*)d_in[0];
  const float* key_in = (const float*)d_in[1];
  const float* value  = (const float*)d_in[2];
  // d_in[3] = mask (int32) — causal, applied analytically
  const float* w_q = (const float*)d_in[4];
  const float* b_q = (const float*)d_in[5];
  const float* w_k = (const float*)d_in[6];
  const float* b_k = (const float*)d_in[7];
  const float* w_v = (const float*)d_in[8];
  const float* b_v = (const float*)d_in[9];
  const float* w_o = (const float*)d_in[10];
  const float* b_o = (const float*)d_in[11];
  float* outp = (float*)d_out;

  const size_t mat = (size_t)MTOT * D_MODEL;  // 4M elems
  bf16* Qws  = (bf16*)d_ws;   // [4096][1024]; attention O aliases this
  bf16* Kws  = Qws + mat;     // [4096][1024]
  bf16* VTws = Kws + mat;     // [1024][4096]  (V transposed, per-head rows)

  dim3 gq(D_MODEL / 128, MTOT / 128, 3);
  gemm_qkv_kernel<<<gq, 256, 0, stream>>>(query, key_in, value, w_q, b_q, w_k,
                                          b_k, w_v, b_v, Qws, Kws, VTws);
  dim3 ga(16, NH, BB);
  attn_kernel<<<ga, 256, 0, stream>>>(Qws, Kws, VTws, Qws);
  dim3 go(D_MODEL / 128, MTOT / 128, 1);
  gemm_out_kernel<<<go, 256, 0, stream>>>(Qws, w_o, b_o, outp);
}

// Round 5
// 293.763 us; speedup vs baseline: 1.3103x; 1.1623x over previous
//
#include <hip/hip_runtime.h>
#include <hip/hip_bf16.h>
#include <type_traits>

#define D_MODEL 1024
#define NH 16
#define DKH 64
#define BB 2
#define SS 2048
#define MTOT (BB * SS)  // 4096

typedef __hip_bfloat16 bf16;
typedef __attribute__((ext_vector_type(8))) short short8;
typedef __attribute__((ext_vector_type(4))) short short4v;
typedef __attribute__((ext_vector_type(4))) float floatx4;

__device__ __forceinline__ bf16 f2bf(float x) { return __float2bfloat16(x); }

// async global->LDS, 16B per lane; LDS dest is wave-uniform base + lane*16
__device__ __forceinline__ void async_cp16(const void* g, void* l) {
  __builtin_amdgcn_global_load_lds(
      (const __attribute__((address_space(1))) unsigned int*)g,
      (__attribute__((address_space(3))) unsigned int*)l, 16, 0, 0);
}

// ---------------------------------------------------------------------------
// GEMM: C[m][n] = sum_k A[m][k] * W[n][k] + bias[n],  M=4096, N=K=1024.
// 128x128 tile, BK=32, 4 waves, 4x4 MFMA 16x16x32 bf16 per wave.
// Staging via global_load_lds (async, m97 2-barrier loop). fp32 tiles go into
// LDS raw with an XOR chunk swizzle (chunk ^= row&7) to break the 32-word-
// stride bank conflict; conversion to bf16 happens after ds_read. bf16 A
// (out-proj) stages straight (2-way pattern, free).
// mode: 0 = bf16 row-major C; 1 = bf16 V^T layout [n][m]; 2 = fp32 C.
// ---------------------------------------------------------------------------
template <typename TIN>
__device__ __forceinline__ void gemm_body(const TIN* __restrict__ A,
                                          const float* __restrict__ W,
                                          const float* __restrict__ Bi,
                                          void* __restrict__ Cv, int mode) {
  constexpr int N = 1024, K = 1024;
  __shared__ TIN As[128 * 32];    // fp32: 16 KB, bf16: 8 KB
  __shared__ float Ws[128 * 32];  // 16 KB

  const int tid = threadIdx.x;
  const int w = tid >> 6, lane = tid & 63, quad = lane >> 4, n16 = lane & 15;
  const int bm = blockIdx.y, bn = blockIdx.x;
  const int wm = (w & 1) * 64, wn = (w >> 1) * 64;

  const int rf = lane >> 3, cf = lane & 7;  // fp32 map: 8 rows x 8 chunks(16B)
  const int rb = lane >> 2, cb = lane & 3;  // bf16 map: 16 rows x 4 chunks(16B)

  const float* Wg0 = W + (size_t)(bn * 128) * K;

  floatx4 acc[4][4] = {};

  for (int k0 = 0; k0 < K; k0 += 32) {
    // ---- issue async staging for this tile ----
    if constexpr (std::is_same<TIN, float>::value) {
      const float* Ag = (const float*)A + (size_t)(bm * 128) * K + k0;
#pragma unroll
      for (int ii = 0; ii < 4; ii++) {
        const int R = w * 32 + ii * 8 + rf;
        async_cp16(Ag + (size_t)R * K + ((cf ^ (R & 7)) * 4),
                   (void*)&As[(w * 32 + ii * 8) * 32]);
      }
    } else {
      const bf16* Ag = (const bf16*)A + (size_t)(bm * 128) * K + k0;
#pragma unroll
      for (int ii = 0; ii < 2; ii++) {
        const int R = w * 32 + ii * 16 + rb;
        async_cp16(Ag + (size_t)R * K + cb * 8,
                   (void*)&As[(w * 32 + ii * 16) * 32]);
      }
    }
    {
      const float* Wg = Wg0 + k0;
#pragma unroll
      for (int ii = 0; ii < 4; ii++) {
        const int R = w * 32 + ii * 8 + rf;
        async_cp16(Wg + (size_t)R * K + ((cf ^ (R & 7)) * 4),
                   (void*)&Ws[(w * 32 + ii * 8) * 32]);
      }
    }
    __syncthreads();  // drains vmcnt(0): tile resident in LDS

    // ---- fragments (convert fp32->bf16 post-ds_read) ----
    short8 af[4], bfr[4];
#pragma unroll
    for (int i = 0; i < 4; i++) {
      const int Rr = wm + i * 16 + n16;
      if constexpr (std::is_same<TIN, float>::value) {
        const float* ap = (const float*)&As[Rr * 32];
        const float4 f0 = *(const float4*)(ap + (((quad * 2 + 0) ^ (Rr & 7)) * 4));
        const float4 f1 = *(const float4*)(ap + (((quad * 2 + 1) ^ (Rr & 7)) * 4));
        bf16* pb = (bf16*)&af[i];
        pb[0] = f2bf(f0.x); pb[1] = f2bf(f0.y); pb[2] = f2bf(f0.z); pb[3] = f2bf(f0.w);
        pb[4] = f2bf(f1.x); pb[5] = f2bf(f1.y); pb[6] = f2bf(f1.z); pb[7] = f2bf(f1.w);
      } else {
        af[i] = *(const short8*)((const bf16*)&As[Rr * 32] + quad * 8);
      }
    }
#pragma unroll
    for (int j = 0; j < 4; j++) {
      const int Rc = wn + j * 16 + n16;
      const float* wp = &Ws[Rc * 32];
      const float4 f0 = *(const float4*)(wp + (((quad * 2 + 0) ^ (Rc & 7)) * 4));
      const float4 f1 = *(const float4*)(wp + (((quad * 2 + 1) ^ (Rc & 7)) * 4));
      bf16* pb = (bf16*)&bfr[j];
      pb[0] = f2bf(f0.x); pb[1] = f2bf(f0.y); pb[2] = f2bf(f0.z); pb[3] = f2bf(f0.w);
      pb[4] = f2bf(f1.x); pb[5] = f2bf(f1.y); pb[6] = f2bf(f1.z); pb[7] = f2bf(f1.w);
    }
#pragma unroll
    for (int i = 0; i < 4; i++)
#pragma unroll
      for (int j = 0; j < 4; j++)
        acc[i][j] = __builtin_amdgcn_mfma_f32_16x16x32_bf16(af[i], bfr[j], acc[i][j], 0, 0, 0);
    __syncthreads();  // all waves done reading before next tile's async writes
  }

  float bv[4];
#pragma unroll
  for (int j = 0; j < 4; j++) bv[j] = Bi[bn * 128 + wn + j * 16 + n16];

#pragma unroll
  for (int i = 0; i < 4; i++) {
    const int rowb = bm * 128 + wm + i * 16 + quad * 4;
#pragma unroll
    for (int j = 0; j < 4; j++) {
      const int col = bn * 128 + wn + j * 16 + n16;
      if (mode == 1) {
        short4v s;
        bf16* pb = (bf16*)&s;
#pragma unroll
        for (int r = 0; r < 4; r++) pb[r] = f2bf(acc[i][j][r] + bv[j]);
        *(short4v*)((bf16*)Cv + (size_t)col * MTOT + rowb) = s;
      } else if (mode == 0) {
        bf16* C = (bf16*)Cv;
#pragma unroll
        for (int r = 0; r < 4; r++)
          C[(size_t)(rowb + r) * N + col] = f2bf(acc[i][j][r] + bv[j]);
      } else {
        float* C = (float*)Cv;
#pragma unroll
        for (int r = 0; r < 4; r++)
          C[(size_t)(rowb + r) * N + col] = acc[i][j][r] + bv[j];
      }
    }
  }
}

__global__ __launch_bounds__(256) void gemm_qkv_kernel(
    const float* __restrict__ q_in, const float* __restrict__ k_in,
    const float* __restrict__ v_in, const float* __restrict__ wq,
    const float* __restrict__ bq, const float* __restrict__ wk,
    const float* __restrict__ bk, const float* __restrict__ wv,
    const float* __restrict__ bv, bf16* __restrict__ Qw,
    bf16* __restrict__ Kw, bf16* __restrict__ VTw) {
  const int z = blockIdx.z;
  const float* A = (z == 0) ? q_in : (z == 1) ? k_in : v_in;
  const float* W = (z == 0) ? wq : (z == 1) ? wk : wv;
  const float* Bi = (z == 0) ? bq : (z == 1) ? bk : bv;
  void* C = (z == 0) ? (void*)Qw : (z == 1) ? (void*)Kw : (void*)VTw;
  gemm_body<float>(A, W, Bi, C, (z == 2) ? 1 : 0);
}

__global__ __launch_bounds__(256) void gemm_out_kernel(
    const bf16* __restrict__ A, const float* __restrict__ W,
    const float* __restrict__ Bi, float* __restrict__ C) {
  gemm_body<bf16>(A, W, Bi, (void*)C, 2);
}

// ---------------------------------------------------------------------------
// Flash attention (unchanged from round 4). Grid (16, NH, BB): block p handles
// q-tiles p and 31-p (uniform 17 KV-iterations). 4 waves x 16 q-rows, BN=128
// KV tiles with reg-prefetch, V pre-transposed by the V-proj GEMM. O aliases Q.
// ---------------------------------------------------------------------------
__global__ __launch_bounds__(256) void attn_kernel(const bf16* __restrict__ Q,
                                                   const bf16* __restrict__ Kg,
                                                   const bf16* __restrict__ VT,
                                                   bf16* __restrict__ O) {
  constexpr int BN = 128, LDK = 72, LDV = 136, LDP = 136;
  __shared__ bf16 Ks[128 * LDK];      // [kv][d]
  __shared__ bf16 Vs[64 * LDV];       // [d][kv]
  __shared__ bf16 Pw[4 * 16 * LDP];   // per-wave P [16][128]

  const int tid = threadIdx.x;
  const int w = tid >> 6, lane = tid & 63, quad = lane >> 4, n16 = lane & 15;
  const int p = blockIdx.x, h = blockIdx.y, b = blockIdx.z;
  const size_t qoff = (size_t)b * SS * D_MODEL + h * DKH;
  const bf16* VTh = VT + (size_t)(h * DKH) * MTOT + (size_t)b * SS;

  const int kvr = tid >> 3, ck = tid & 7;  // K staging (+32 rows per ii)
  const int dd = tid >> 4, cv = tid & 15;  // V staging (+16 rows per ii)

  short8 kreg[4], vreg[4];
  auto loadKV = [&](int kv0) {
#pragma unroll
    for (int ii = 0; ii < 4; ii++) {
      kreg[ii] = *(const short8*)(Kg + qoff + (size_t)(kv0 + ii * 32 + kvr) * D_MODEL + ck * 8);
      vreg[ii] = *(const short8*)(VTh + (size_t)(ii * 16 + dd) * MTOT + kv0 + cv * 8);
    }
  };

  for (int hf = 0; hf < 2; hf++) {
    const int q0 = (hf == 0) ? p * 64 : (31 - p) * 64;
    const int q0w = q0 + w * 16;
    const int nt = (q0 + 191) >> 7;

    short8 aQ0, aQ1;
    {
      const bf16* qp = Q + qoff + (size_t)(q0w + n16) * D_MODEL + quad * 8;
      aQ0 = *(const short8*)(qp);
      aQ1 = *(const short8*)(qp + 32);
    }

    floatx4 facc[4] = {};
    float m_i[4], l_i[4];
#pragma unroll
    for (int r = 0; r < 4; r++) { m_i[r] = -1e30f; l_i[r] = 0.f; }

    loadKV(0);
    for (int t = 0; t < nt; t++) {
#pragma unroll
      for (int ii = 0; ii < 4; ii++) {
        *(short8*)(&Ks[(ii * 32 + kvr) * LDK + ck * 8]) = kreg[ii];
        *(short8*)(&Vs[(ii * 16 + dd) * LDV + cv * 8]) = vreg[ii];
      }
      __syncthreads();
      if (t + 1 < nt) loadKV((t + 1) * BN);

      const int kv0 = t * BN;
      float pv[8][4];
      float mt[4] = {-1e30f, -1e30f, -1e30f, -1e30f};
      const int qrow_base = q0w + quad * 4;
#pragma unroll
      for (int blk = 0; blk < 8; blk++) {
        floatx4 z = {};
        short8 bk0 = *(const short8*)(&Ks[(blk * 16 + n16) * LDK + quad * 8]);
        short8 bk1 = *(const short8*)(&Ks[(blk * 16 + n16) * LDK + 32 + quad * 8]);
        z = __builtin_amdgcn_mfma_f32_16x16x32_bf16(aQ0, bk0, z, 0, 0, 0);
        z = __builtin_amdgcn_mfma_f32_16x16x32_bf16(aQ1, bk1, z, 0, 0, 0);
        const int kvg = kv0 + blk * 16 + n16;
#pragma unroll
        for (int r = 0; r < 4; r++) {
          float s = z[r] * 0.125f;
          if (kvg > qrow_base + r) s = -1e30f;
          pv[blk][r] = s;
          mt[r] = fmaxf(mt[r], s);
        }
      }
#pragma unroll
      for (int off = 1; off < 16; off <<= 1)
#pragma unroll
        for (int r = 0; r < 4; r++) mt[r] = fmaxf(mt[r], __shfl_xor(mt[r], off, 64));

      float alpha[4];
#pragma unroll
      for (int r = 0; r < 4; r++) {
        const float mn = fmaxf(m_i[r], mt[r]);
        alpha[r] = __expf(m_i[r] - mn);
        m_i[r] = mn;
      }
      float rs[4] = {0.f, 0.f, 0.f, 0.f};
#pragma unroll
      for (int blk = 0; blk < 8; blk++)
#pragma unroll
        for (int r = 0; r < 4; r++) {
          const float pe = __expf(pv[blk][r] - m_i[r]);
          pv[blk][r] = pe;
          rs[r] += pe;
        }
#pragma unroll
      for (int off = 1; off < 16; off <<= 1)
#pragma unroll
        for (int r = 0; r < 4; r++) rs[r] += __shfl_xor(rs[r], off, 64);
#pragma unroll
      for (int r = 0; r < 4; r++) l_i[r] = l_i[r] * alpha[r] + rs[r];
#pragma unroll
      for (int d = 0; d < 4; d++)
#pragma unroll
        for (int r = 0; r < 4; r++) facc[d][r] *= alpha[r];

      bf16* pw = &Pw[w * 16 * LDP];
#pragma unroll
      for (int blk = 0; blk < 8; blk++)
#pragma unroll
        for (int r = 0; r < 4; r++)
          pw[(quad * 4 + r) * LDP + blk * 16 + n16] = f2bf(pv[blk][r]);

      short8 aP[4];
#pragma unroll
      for (int c = 0; c < 4; c++)
        aP[c] = *(const short8*)(&pw[n16 * LDP + c * 32 + quad * 8]);

#pragma unroll
      for (int d = 0; d < 4; d++)
#pragma unroll
        for (int c = 0; c < 4; c++) {
          short8 bvf = *(const short8*)(&Vs[(d * 16 + n16) * LDV + c * 32 + quad * 8]);
          facc[d] = __builtin_amdgcn_mfma_f32_16x16x32_bf16(aP[c], bvf, facc[d], 0, 0, 0);
        }
      __syncthreads();
    }

#pragma unroll
    for (int r = 0; r < 4; r++) {
      const float inv = 1.f / l_i[r];
      const int qrow = q0w + quad * 4 + r;
      bf16* op = O + qoff + (size_t)qrow * D_MODEL;
#pragma unroll
      for (int d = 0; d < 4; d++) op[d * 16 + n16] = f2bf(facc[d][r] * inv);
    }
  }
}

// ---------------------------------------------------------------------------
extern "C" void kernel_launch(void* const* d_in, const int* in_sizes, int n_in,
                              void* d_out, int out_size, void* d_ws, size_t ws_size,
                              hipStream_t stream) {
  (void)in_sizes; (void)n_in; (void)out_size; (void)ws_size;
  const float* query  = (const float*)d_in[0];
  const float* key_in = (const float*)d_in[1];
  const float* value  = (const float*)d_in[2];
  // d_in[3] = mask (int32) — causal, applied analytically
  const float* w_q = (const float*)d_in[4];
  const float* b_q = (const float*)d_in[5];
  const float* w_k = (const float*)d_in[6];
  const float* b_k = (const float*)d_in[7];
  const float* w_v = (const float*)d_in[8];
  const float* b_v = (const float*)d_in[9];
  const float* w_o = (const float*)d_in[10];
  const float* b_o = (const float*)d_in[11];
  float* outp = (float*)d_out;

  const size_t mat = (size_t)MTOT * D_MODEL;  // 4M elems
  bf16* Qws  = (bf16*)d_ws;   // [4096][1024]; attention O aliases this
  bf16* Kws  = Qws + mat;     // [4096][1024]
  bf16* VTws = Kws + mat;     // [1024][4096]  (V transposed, per-head rows)

  dim3 gq(D_MODEL / 128, MTOT / 128, 3);
  gemm_qkv_kernel<<<gq, 256, 0, stream>>>(query, key_in, value, w_q, b_q, w_k,
                                          b_k, w_v, b_v, Qws, Kws, VTws);
  dim3 ga(16, NH, BB);
  attn_kernel<<<ga, 256, 0, stream>>>(Qws, Kws, VTws, Qws);
  dim3 go(D_MODEL / 128, MTOT / 128, 1);
  gemm_out_kernel<<<go, 256, 0, stream>>>(Qws, w_o, b_o, outp);
}

// Round 6
// 264.773 us; speedup vs baseline: 1.4538x; 1.1095x over previous
//
#include <hip/hip_runtime.h>
#include <hip/hip_bf16.h>
#include <type_traits>

#define D_MODEL 1024
#define NH 16
#define DKH 64
#define BB 2
#define SS 2048
#define MTOT (BB * SS)  // 4096

typedef __hip_bfloat16 bf16;
typedef __attribute__((ext_vector_type(8))) short short8;
typedef __attribute__((ext_vector_type(4))) short short4v;
typedef __attribute__((ext_vector_type(4))) float floatx4;

__device__ __forceinline__ bf16 f2bf(float x) { return __float2bfloat16(x); }

// async global->LDS, 16B per lane; LDS dest must be wave-uniform (HW adds lane*16)
__device__ __forceinline__ void async_cp16(const void* g, void* l) {
  __builtin_amdgcn_global_load_lds(
      (const __attribute__((address_space(1))) unsigned int*)g,
      (__attribute__((address_space(3))) unsigned int*)l, 16, 0, 0);
}

// ---------------------------------------------------------------------------
// Weight pre-conversion: w_q|w_k|w_v|w_o fp32 -> bf16 (4 x 1M elems).
// Weights are the cross-XCD-replicated operand; halving their bytes halves
// the replicated HBM traffic AND halves GEMM staging bytes per iter.
// ---------------------------------------------------------------------------
__global__ __launch_bounds__(256) void convert_w_kernel(
    const float* __restrict__ wq, const float* __restrict__ wk,
    const float* __restrict__ wv, const float* __restrict__ wo,
    bf16* __restrict__ out) {
  const int id = blockIdx.x * 256 + threadIdx.x;  // float4 index, 0..1M-1
  const int m = id >> 18;                         // matrix 0..3
  const int loc = id & 262143;
  const float* src = (m == 0) ? wq : (m == 1) ? wk : (m == 2) ? wv : wo;
  const float4 v = *(const float4*)(src + (size_t)loc * 4);
  short4v s;
  bf16* pb = (bf16*)&s;
  pb[0] = f2bf(v.x); pb[1] = f2bf(v.y); pb[2] = f2bf(v.z); pb[3] = f2bf(v.w);
  *(short4v*)(out + ((size_t)m << 20) + (size_t)loc * 4) = s;
}

// ---------------------------------------------------------------------------
// GEMM: C[m][n] = sum_k A[m][k] * W[n][k] + bias[n],  M=4096, N=K=1024.
// 128x128 tile, BK=32, 4 waves, 4x4 MFMA 16x16x32 bf16 per wave.
// Async double-buffered K-loop (ONE barrier/iter):
//   barrier(drain buf) -> issue(buf^1, k+1) -> compute(buf)
// so next tile's global_load_lds are in flight during the whole MFMA phase.
// A fp32 staged raw with XOR chunk swizzle (chunk ^= row&7, 2-way = free);
// W always bf16 (pre-converted, m97 16B pattern).
// blockIdx.x is bm-fastest (bm = x&31): the 8 bn-blocks sharing an A-tile get
// the same id%8 residue -> same XCD -> A fetched ~once per XCD.
// mode: 0 = bf16 row-major C; 1 = bf16 V^T layout [n][m]; 2 = fp32 C.
// ---------------------------------------------------------------------------
template <typename TIN>
__device__ __forceinline__ void gemm_body(const TIN* __restrict__ A,
                                          const bf16* __restrict__ W,
                                          const float* __restrict__ Bi,
                                          void* __restrict__ Cv, int mode) {
  constexpr int N = 1024, K = 1024;
  __shared__ TIN As[2][128 * 32];   // fp32: 32 KB total, bf16: 16 KB
  __shared__ bf16 Ws[2][128 * 32];  // 16 KB total

  const int tid = threadIdx.x;
  const int w = tid >> 6, lane = tid & 63, quad = lane >> 4, n16 = lane & 15;
  const int bx = blockIdx.x;
  const int bm = bx & 31, bn = bx >> 5;  // bm-fastest (XCD locality for A)
  const int wm = (w & 1) * 64, wn = (w >> 1) * 64;

  const int rf = lane >> 3, cf = lane & 7;  // fp32 map: 8 rows x 8 chunks(16B)
  const int rb = lane >> 2, cb = lane & 3;  // bf16 map: 16 rows x 4 chunks(16B)

  const bf16* Wg0 = W + (size_t)(bn * 128) * K;

  auto issue = [&](int buf, int k0) {
    if constexpr (std::is_same<TIN, float>::value) {
      const float* Ag = (const float*)A + (size_t)(bm * 128) * K + k0;
#pragma unroll
      for (int ii = 0; ii < 4; ii++) {
        const int R = w * 32 + ii * 8 + rf;
        async_cp16(Ag + (size_t)R * K + ((cf ^ (R & 7)) * 4),
                   (void*)&As[buf][(w * 32 + ii * 8) * 32]);
      }
    } else {
      const bf16* Ag = (const bf16*)A + (size_t)(bm * 128) * K + k0;
#pragma unroll
      for (int ii = 0; ii < 2; ii++) {
        const int R = w * 32 + ii * 16 + rb;
        async_cp16(Ag + (size_t)R * K + cb * 8,
                   (void*)&As[buf][(w * 32 + ii * 16) * 32]);
      }
    }
    const bf16* Wg = Wg0 + k0;
#pragma unroll
    for (int ii = 0; ii < 2; ii++) {
      const int R = w * 32 + ii * 16 + rb;
      async_cp16(Wg + (size_t)R * K + cb * 8,
                 (void*)&Ws[buf][(w * 32 + ii * 16) * 32]);
    }
  };

  floatx4 acc[4][4] = {};
  issue(0, 0);
  int buf = 0;
  for (int k0 = 0; k0 < K; k0 += 32) {
    __syncthreads();  // drains this wave's async loads for As/Ws[buf]
    if (k0 + 32 < K) issue(buf ^ 1, k0 + 32);  // in flight during compute

    short8 af[4], bfr[4];
#pragma unroll
    for (int i = 0; i < 4; i++) {
      const int Rr = wm + i * 16 + n16;
      if constexpr (std::is_same<TIN, float>::value) {
        const float* ap = (const float*)&As[buf][Rr * 32];
        const float4 f0 = *(const float4*)(ap + (((quad * 2 + 0) ^ (Rr & 7)) * 4));
        const float4 f1 = *(const float4*)(ap + (((quad * 2 + 1) ^ (Rr & 7)) * 4));
        bf16* pb = (bf16*)&af[i];
        pb[0] = f2bf(f0.x); pb[1] = f2bf(f0.y); pb[2] = f2bf(f0.z); pb[3] = f2bf(f0.w);
        pb[4] = f2bf(f1.x); pb[5] = f2bf(f1.y); pb[6] = f2bf(f1.z); pb[7] = f2bf(f1.w);
      } else {
        af[i] = *(const short8*)((const bf16*)&As[buf][Rr * 32] + quad * 8);
      }
    }
#pragma unroll
    for (int j = 0; j < 4; j++)
      bfr[j] = *(const short8*)(&Ws[buf][(wn + j * 16 + n16) * 32 + quad * 8]);
#pragma unroll
    for (int i = 0; i < 4; i++)
#pragma unroll
      for (int j = 0; j < 4; j++)
        acc[i][j] = __builtin_amdgcn_mfma_f32_16x16x32_bf16(af[i], bfr[j], acc[i][j], 0, 0, 0);
    buf ^= 1;
  }

  float bv[4];
#pragma unroll
  for (int j = 0; j < 4; j++) bv[j] = Bi[bn * 128 + wn + j * 16 + n16];

#pragma unroll
  for (int i = 0; i < 4; i++) {
    const int rowb = bm * 128 + wm + i * 16 + quad * 4;
#pragma unroll
    for (int j = 0; j < 4; j++) {
      const int col = bn * 128 + wn + j * 16 + n16;
      if (mode == 1) {
        short4v s;
        bf16* pb = (bf16*)&s;
#pragma unroll
        for (int r = 0; r < 4; r++) pb[r] = f2bf(acc[i][j][r] + bv[j]);
        *(short4v*)((bf16*)Cv + (size_t)col * MTOT + rowb) = s;
      } else if (mode == 0) {
        bf16* C = (bf16*)Cv;
#pragma unroll
        for (int r = 0; r < 4; r++)
          C[(size_t)(rowb + r) * N + col] = f2bf(acc[i][j][r] + bv[j]);
      } else {
        float* C = (float*)Cv;
#pragma unroll
        for (int r = 0; r < 4; r++)
          C[(size_t)(rowb + r) * N + col] = acc[i][j][r] + bv[j];
      }
    }
  }
}

__global__ __launch_bounds__(256) void gemm_qkv_kernel(
    const float* __restrict__ q_in, const float* __restrict__ k_in,
    const float* __restrict__ v_in, const bf16* __restrict__ Wb,
    const float* __restrict__ bq, const float* __restrict__ bk,
    const float* __restrict__ bv, bf16* __restrict__ Qw,
    bf16* __restrict__ Kw, bf16* __restrict__ VTw) {
  const int z = blockIdx.z;
  const float* A = (z == 0) ? q_in : (z == 1) ? k_in : v_in;
  const bf16* W = Wb + ((size_t)z << 20);
  const float* Bi = (z == 0) ? bq : (z == 1) ? bk : bv;
  void* C = (z == 0) ? (void*)Qw : (z == 1) ? (void*)Kw : (void*)VTw;
  gemm_body<float>(A, W, Bi, C, (z == 2) ? 1 : 0);
}

__global__ __launch_bounds__(256) void gemm_out_kernel(
    const bf16* __restrict__ A, const bf16* __restrict__ W,
    const float* __restrict__ Bi, float* __restrict__ C) {
  gemm_body<bf16>(A, W, Bi, (void*)C, 2);
}

// ---------------------------------------------------------------------------
// Flash attention. Grid (NH*BB, 16): x = head-batch (fastest -> id%8 groups a
// head's 16 blocks onto one XCD for K/V L2 reuse), y = q-pair index p; block
// handles q-tiles p and 31-p (uniform 17 KV-iterations). 4 waves x 16 q-rows,
// BN=128 KV tiles, reg-prefetch, V pre-transposed by V-proj GEMM. O aliases Q.
// ---------------------------------------------------------------------------
__global__ __launch_bounds__(256) void attn_kernel(const bf16* __restrict__ Q,
                                                   const bf16* __restrict__ Kg,
                                                   const bf16* __restrict__ VT,
                                                   bf16* __restrict__ O) {
  constexpr int BN = 128, LDK = 72, LDV = 136, LDP = 136;
  __shared__ bf16 Ks[128 * LDK];
  __shared__ bf16 Vs[64 * LDV];
  __shared__ bf16 Pw[4 * 16 * LDP];

  const int tid = threadIdx.x;
  const int w = tid >> 6, lane = tid & 63, quad = lane >> 4, n16 = lane & 15;
  const int hb = blockIdx.x;
  const int h = hb & 15, b = hb >> 4, p = blockIdx.y;
  const size_t qoff = (size_t)b * SS * D_MODEL + h * DKH;
  const bf16* VTh = VT + (size_t)(h * DKH) * MTOT + (size_t)b * SS;

  const int kvr = tid >> 3, ck = tid & 7;
  const int dd = tid >> 4, cv = tid & 15;

  short8 kreg[4], vreg[4];
  auto loadKV = [&](int kv0) {
#pragma unroll
    for (int ii = 0; ii < 4; ii++) {
      kreg[ii] = *(const short8*)(Kg + qoff + (size_t)(kv0 + ii * 32 + kvr) * D_MODEL + ck * 8);
      vreg[ii] = *(const short8*)(VTh + (size_t)(ii * 16 + dd) * MTOT + kv0 + cv * 8);
    }
  };

  for (int hf = 0; hf < 2; hf++) {
    const int q0 = (hf == 0) ? p * 64 : (31 - p) * 64;
    const int q0w = q0 + w * 16;
    const int nt = (q0 + 191) >> 7;

    short8 aQ0, aQ1;
    {
      const bf16* qp = Q + qoff + (size_t)(q0w + n16) * D_MODEL + quad * 8;
      aQ0 = *(const short8*)(qp);
      aQ1 = *(const short8*)(qp + 32);
    }

    floatx4 facc[4] = {};
    float m_i[4], l_i[4];
#pragma unroll
    for (int r = 0; r < 4; r++) { m_i[r] = -1e30f; l_i[r] = 0.f; }

    loadKV(0);
    for (int t = 0; t < nt; t++) {
#pragma unroll
      for (int ii = 0; ii < 4; ii++) {
        *(short8*)(&Ks[(ii * 32 + kvr) * LDK + ck * 8]) = kreg[ii];
        *(short8*)(&Vs[(ii * 16 + dd) * LDV + cv * 8]) = vreg[ii];
      }
      __syncthreads();
      if (t + 1 < nt) loadKV((t + 1) * BN);

      const int kv0 = t * BN;
      float pv[8][4];
      float mt[4] = {-1e30f, -1e30f, -1e30f, -1e30f};
      const int qrow_base = q0w + quad * 4;
#pragma unroll
      for (int blk = 0; blk < 8; blk++) {
        floatx4 z = {};
        short8 bk0 = *(const short8*)(&Ks[(blk * 16 + n16) * LDK + quad * 8]);
        short8 bk1 = *(const short8*)(&Ks[(blk * 16 + n16) * LDK + 32 + quad * 8]);
        z = __builtin_amdgcn_mfma_f32_16x16x32_bf16(aQ0, bk0, z, 0, 0, 0);
        z = __builtin_amdgcn_mfma_f32_16x16x32_bf16(aQ1, bk1, z, 0, 0, 0);
        const int kvg = kv0 + blk * 16 + n16;
#pragma unroll
        for (int r = 0; r < 4; r++) {
          float s = z[r] * 0.125f;
          if (kvg > qrow_base + r) s = -1e30f;
          pv[blk][r] = s;
          mt[r] = fmaxf(mt[r], s);
        }
      }
#pragma unroll
      for (int off = 1; off < 16; off <<= 1)
#pragma unroll
        for (int r = 0; r < 4; r++) mt[r] = fmaxf(mt[r], __shfl_xor(mt[r], off, 64));

      float alpha[4];
#pragma unroll
      for (int r = 0; r < 4; r++) {
        const float mn = fmaxf(m_i[r], mt[r]);
        alpha[r] = __expf(m_i[r] - mn);
        m_i[r] = mn;
      }
      float rs[4] = {0.f, 0.f, 0.f, 0.f};
#pragma unroll
      for (int blk = 0; blk < 8; blk++)
#pragma unroll
        for (int r = 0; r < 4; r++) {
          const float pe = __expf(pv[blk][r] - m_i[r]);
          pv[blk][r] = pe;
          rs[r] += pe;
        }
#pragma unroll
      for (int off = 1; off < 16; off <<= 1)
#pragma unroll
        for (int r = 0; r < 4; r++) rs[r] += __shfl_xor(rs[r], off, 64);
#pragma unroll
      for (int r = 0; r < 4; r++) l_i[r] = l_i[r] * alpha[r] + rs[r];
#pragma unroll
      for (int d = 0; d < 4; d++)
#pragma unroll
        for (int r = 0; r < 4; r++) facc[d][r] *= alpha[r];

      bf16* pw = &Pw[w * 16 * LDP];
#pragma unroll
      for (int blk = 0; blk < 8; blk++)
#pragma unroll
        for (int r = 0; r < 4; r++)
          pw[(quad * 4 + r) * LDP + blk * 16 + n16] = f2bf(pv[blk][r]);

      short8 aP[4];
#pragma unroll
      for (int c = 0; c < 4; c++)
        aP[c] = *(const short8*)(&pw[n16 * LDP + c * 32 + quad * 8]);

#pragma unroll
      for (int d = 0; d < 4; d++)
#pragma unroll
        for (int c = 0; c < 4; c++) {
          short8 bvf = *(const short8*)(&Vs[(d * 16 + n16) * LDV + c * 32 + quad * 8]);
          facc[d] = __builtin_amdgcn_mfma_f32_16x16x32_bf16(aP[c], bvf, facc[d], 0, 0, 0);
        }
      __syncthreads();
    }

#pragma unroll
    for (int r = 0; r < 4; r++) {
      const float inv = 1.f / l_i[r];
      const int qrow = q0w + quad * 4 + r;
      bf16* op = O + qoff + (size_t)qrow * D_MODEL;
#pragma unroll
      for (int d = 0; d < 4; d++) op[d * 16 + n16] = f2bf(facc[d][r] * inv);
    }
  }
}

// ---------------------------------------------------------------------------
extern "C" void kernel_launch(void* const* d_in, const int* in_sizes, int n_in,
                              void* d_out, int out_size, void* d_ws, size_t ws_size,
                              hipStream_t stream) {
  (void)in_sizes; (void)n_in; (void)out_size; (void)ws_size;
  const float* query  = (const float*)d_in[0];
  const float* key_in = (const float*)d_in[1];
  const float* value  = (const float*)d_in[2];
  // d_in[3] = mask (int32) — causal, applied analytically
  const float* w_q = (const float*)d_in[4];
  const float* b_q = (const float*)d_in[5];
  const float* w_k = (const float*)d_in[6];
  const float* b_k = (const float*)d_in[7];
  const float* w_v = (const float*)d_in[8];
  const float* b_v = (const float*)d_in[9];
  const float* w_o = (const float*)d_in[10];
  const float* b_o = (const float*)d_in[11];
  float* outp = (float*)d_out;

  const size_t mat = (size_t)MTOT * D_MODEL;  // 4M elems
  bf16* Qws  = (bf16*)d_ws;   // 8 MB; attention O aliases this
  bf16* Kws  = Qws + mat;     // 8 MB
  bf16* VTws = Kws + mat;     // 8 MB (V transposed, per-head rows)
  bf16* Wb   = VTws + mat;    // 8 MB: wq|wk|wv|wo bf16, 1M elems each

  convert_w_kernel<<<4096, 256, 0, stream>>>(w_q, w_k, w_v, w_o, Wb);

  dim3 gq(256, 1, 3);  // x = bm + 32*bn (bm-fastest)
  gemm_qkv_kernel<<<gq, 256, 0, stream>>>(query, key_in, value, Wb, b_q, b_k,
                                          b_v, Qws, Kws, VTws);
  dim3 ga(NH * BB, 16);  // x = head-batch (fastest), y = q-pair
  attn_kernel<<<ga, 256, 0, stream>>>(Qws, Kws, VTws, Qws);
  dim3 go(256, 1, 1);
  gemm_out_kernel<<<go, 256, 0, stream>>>(Qws, Wb + ((size_t)3 << 20), b_o, outp);
}